// Round 2
// baseline (323.818 us; speedup 1.0000x reference)
//
#include <hip/hip_runtime.h>

#define TFULL 4092
#define NB    64
#define CH    16
#define OUT_T 2048
#define TOFF  2044   // TFULL - OUT_T

// ---------------- Layer 0: conv(4->16,K=3,d=1) + relu + io + mixer-init ----------------
__global__ __launch_bounds__(256) void layer0_kernel(
    const float* __restrict__ input,   // (B, T, 4)
    const float* __restrict__ w,       // (3, 4, 16)
    const float* __restrict__ bias,    // (16)
    const float* __restrict__ iow,     // (16, 16)  = io_w[0]
    const float* __restrict__ iob,     // (16)
    const float* __restrict__ mw,      // (16)  mixer slice for layer 0
    const float* __restrict__ mb,      // (1)   mixer bias
    float* __restrict__ sig_out,       // (B, T, 16)
    float* __restrict__ out)           // (B, 2048)
{
    const int b = blockIdx.y;
    const int t = blockIdx.x * 256 + threadIdx.x;
    if (t >= TFULL) return;
    const float* ib = input + ((size_t)b * TFULL) * 4;

    float h[CH];
    #pragma unroll
    for (int o = 0; o < CH; ++o) h[o] = bias[o];

    float sig_t = 0.f;
    #pragma unroll
    for (int k = 0; k < 3; ++k) {
        const int tt = t - (2 - k);            // dilation 1
        if (tt >= 0) {                         // zero-pad: skip contributes 0
            const float4 x = *(const float4*)(ib + (size_t)tt * 4);
            if (k == 2) sig_t = x.x;
            const float xv[4] = {x.x, x.y, x.z, x.w};
            #pragma unroll
            for (int c = 0; c < 4; ++c) {
                const float v = xv[c];
                #pragma unroll
                for (int o = 0; o < CH; ++o)
                    h[o] = fmaf(v, w[(k * 4 + c) * CH + o], h[o]);
            }
        }
    }
    #pragma unroll
    for (int o = 0; o < CH; ++o) h[o] = fmaxf(h[o], 0.f);

    if (t >= TOFF) {
        float m = mb[0];
        #pragma unroll
        for (int o = 0; o < CH; ++o) m = fmaf(h[o], mw[o], m);
        out[(size_t)b * OUT_T + (t - TOFF)] = m;   // WRITE (first layer initializes)
    }

    // signal_1 = h @ iow + iob + sig_t/2   (layer-0 signal has 1 channel)
    float sn[CH];
    const float half = sig_t * 0.5f;
    #pragma unroll
    for (int o = 0; o < CH; ++o) sn[o] = iob[o] + half;
    #pragma unroll
    for (int c = 0; c < CH; ++c) {
        const float v = h[c];
        #pragma unroll
        for (int o = 0; o < CH; ++o)
            sn[o] = fmaf(v, iow[c * CH + o], sn[o]);
    }
    float* op = sig_out + ((size_t)b * TFULL + t) * CH;
    *(float4*)(op + 0)  = make_float4(sn[0],  sn[1],  sn[2],  sn[3]);
    *(float4*)(op + 4)  = make_float4(sn[4],  sn[5],  sn[6],  sn[7]);
    *(float4*)(op + 8)  = make_float4(sn[8],  sn[9],  sn[10], sn[11]);
    *(float4*)(op + 12) = make_float4(sn[12], sn[13], sn[14], sn[15]);
}

// ---------------- Layers 1..17: conv(19->16,K=3,dil d) + relu (+ io) + mixer-accum ----------------
template <bool HAS_IO>
__global__ __launch_bounds__(256) void layer_kernel(
    const float* __restrict__ input,   // (B, T, 4)  -> controls in ch 1..3
    const float* __restrict__ sig_in,  // (B, T, 16)
    const float* __restrict__ w,       // (3, 19, 16)
    const float* __restrict__ bias,    // (16)
    const float* __restrict__ iow,     // (16, 16)  (unused if !HAS_IO)
    const float* __restrict__ iob,     // (16)
    const float* __restrict__ mw,      // (16)
    float* __restrict__ sig_out,       // (B, T, 16) (unused if !HAS_IO)
    float* __restrict__ out,           // (B, 2048)
    int dil, int t_start)
{
    const int b = blockIdx.y;
    const int t = t_start + blockIdx.x * 256 + threadIdx.x;
    if (t >= TFULL) return;
    const float* ib = input  + ((size_t)b * TFULL) * 4;
    const float* sb = sig_in + ((size_t)b * TFULL) * CH;

    float h[CH];
    #pragma unroll
    for (int o = 0; o < CH; ++o) h[o] = bias[o];

    float sum_t = 0.f;
    #pragma unroll
    for (int k = 0; k < 3; ++k) {
        const int tt = t - (2 - k) * dil;
        if (tt >= 0) {                         // zero-pad: skip contributes 0
            const float4* sp = (const float4*)(sb + (size_t)tt * CH);
            const float4 s0 = sp[0], s1 = sp[1], s2 = sp[2], s3 = sp[3];
            const float sv[CH] = {s0.x, s0.y, s0.z, s0.w, s1.x, s1.y, s1.z, s1.w,
                                  s2.x, s2.y, s2.z, s2.w, s3.x, s3.y, s3.z, s3.w};
            const float4 cc = *(const float4*)(ib + (size_t)tt * 4);
            if (k == 2) {
                float acc = 0.f;
                #pragma unroll
                for (int c = 0; c < CH; ++c) acc += sv[c];
                sum_t = acc;
            }
            #pragma unroll
            for (int c = 0; c < CH; ++c) {
                const float v = sv[c];
                #pragma unroll
                for (int o = 0; o < CH; ++o)
                    h[o] = fmaf(v, w[(k * 19 + c) * CH + o], h[o]);
            }
            const float cv[3] = {cc.y, cc.z, cc.w};
            #pragma unroll
            for (int c = 0; c < 3; ++c) {
                const float v = cv[c];
                #pragma unroll
                for (int o = 0; o < CH; ++o)
                    h[o] = fmaf(v, w[(k * 19 + 16 + c) * CH + o], h[o]);
            }
        }
    }
    #pragma unroll
    for (int o = 0; o < CH; ++o) h[o] = fmaxf(h[o], 0.f);

    if (t >= TOFF) {
        float m = 0.f;
        #pragma unroll
        for (int o = 0; o < CH; ++o) m = fmaf(h[o], mw[o], m);
        const size_t oi = (size_t)b * OUT_T + (t - TOFF);
        out[oi] += m;     // unique (b,t) per thread; stream-ordered across layers
    }

    if (HAS_IO) {
        float sn[CH];
        const float half = sum_t * 0.5f;
        #pragma unroll
        for (int o = 0; o < CH; ++o) sn[o] = iob[o] + half;
        #pragma unroll
        for (int c = 0; c < CH; ++c) {
            const float v = h[c];
            #pragma unroll
            for (int o = 0; o < CH; ++o)
                sn[o] = fmaf(v, iow[c * CH + o], sn[o]);
        }
        float* op = sig_out + ((size_t)b * TFULL + t) * CH;
        *(float4*)(op + 0)  = make_float4(sn[0],  sn[1],  sn[2],  sn[3]);
        *(float4*)(op + 4)  = make_float4(sn[4],  sn[5],  sn[6],  sn[7]);
        *(float4*)(op + 8)  = make_float4(sn[8],  sn[9],  sn[10], sn[11]);
        *(float4*)(op + 12) = make_float4(sn[12], sn[13], sn[14], sn[15]);
    }
}

extern "C" void kernel_launch(void* const* d_in, const int* in_sizes, int n_in,
                              void* d_out, int out_size, void* d_ws, size_t ws_size,
                              hipStream_t stream) {
    const float* input   = (const float*)d_in[0];  // (64, 4092, 4)
    const float* conv_w0 = (const float*)d_in[1];  // (3, 4, 16)
    const float* conv_w  = (const float*)d_in[2];  // (17, 3, 19, 16)
    const float* conv_b  = (const float*)d_in[3];  // (18, 16)
    const float* io_w    = (const float*)d_in[4];  // (17, 16, 16)  -> layer i uses io_w[i], i=0..16
    const float* io_b    = (const float*)d_in[5];  // (17, 16)
    const float* mixer_w = (const float*)d_in[6];  // (288, 1)
    const float* mixer_b = (const float*)d_in[7];  // (1,)
    float* out = (float*)d_out;                    // (64, 2048) fp32

    float* sigA = (float*)d_ws;                           // (B,T,16)
    float* sigB = sigA + (size_t)NB * TFULL * CH;         // (B,T,16)

    static const int dil[18] = {1,2,4,8,16,32,64,128,256, 1,2,4,8,16,32,64,128,256};
    // first needed t per layer (backward receptive-field trim); negative taps zero-guarded
    static const int ts[18]  = {0,2,6,14,30,62,126,254,510,
                                1022,1024,1028,1036,1052,1084,1148,1276,1532};
    // note ts[17] is for layer 17's INPUT needs handled below; layer 17 itself runs t>=2044
    static const int ts17 = 2044;

    {   // layer 0 (runs full range t>=0)
        dim3 grid((TFULL + 255) / 256, NB);
        layer0_kernel<<<grid, 256, 0, stream>>>(input, conv_w0, conv_b, io_w, io_b,
                                                mixer_w, mixer_b, sigA, out);
    }
    const float* cur = sigA;
    float* nxt = sigB;
    for (int i = 1; i < 18; ++i) {
        const int t0 = (i == 17) ? ts17 : ts[i];
        const int len = TFULL - t0;
        dim3 grid((len + 255) / 256, NB);
        const float* wl = conv_w + (size_t)(i - 1) * 3 * 19 * 16;
        if (i < 17) {
            layer_kernel<true><<<grid, 256, 0, stream>>>(
                input, cur, wl, conv_b + i * CH,
                io_w + (size_t)i * CH * CH, io_b + (size_t)i * CH,   // io_w[i] !
                mixer_w + i * CH, nxt, out, dil[i], t0);
        } else {
            layer_kernel<false><<<grid, 256, 0, stream>>>(
                input, cur, wl, conv_b + i * CH,
                nullptr, nullptr,
                mixer_w + i * CH, nullptr, out, dil[i], t0);
        }
        float* tmp = (float*)cur; cur = nxt; nxt = tmp;
    }
}